// Round 11
// baseline (237.733 us; speedup 1.0000x reference)
//
#include <hip/hip_runtime.h>
#include <hip/hip_fp16.h>

#define DFEAT 64
#define NG 64
#define TILE 128        // nodes per bucket/tile (bucket = tgt >> 7)
#define NBLK 256        // binning blocks
#define NBMAX 1024      // max buckets supported in LDS

// ------ pass A (fused): zero S/T/cntf + bucket histogram + fp32->fp16 convert ---
__global__ __launch_bounds__(256) void k_cnt(const int* __restrict__ col,
                                             int* __restrict__ cnt_m,
                                             float* __restrict__ zeroreg,
                                             const float* __restrict__ x,
                                             __half2* __restrict__ xh,
                                             int e, int nb, int chunk, int n32) {
  __shared__ int hist[NBMAX];
  int tid = threadIdx.x;
  int blk = blockIdx.x;
  if (blk == 0) {
    for (int i = tid; i < 4224; i += 256) zeroreg[i] = 0.f;  // S+cntf+T
  }
  for (int b = tid; b < nb; b += 256) hist[b] = 0;
  __syncthreads();
  int lo = blk * chunk, hi = min(lo + chunk, e);
  for (int i = lo + tid; i < hi; i += 256)
    atomicAdd(&hist[col[i] >> 7], 1);
  __syncthreads();
  for (int b = tid; b < nb; b += 256)
    cnt_m[(size_t)blk * nb + b] = hist[b];
  // fused fp16 conversion (grid-stride)
  for (int i = blk * 256 + tid; i < n32; i += NBLK * 256) {
    float2 v = ((const float2*)x)[i];
    xh[i] = __float22half2_rn(v);
  }
}

// ---------------- pass B: per-bucket scan over blocks (in place) + totals -------
__global__ __launch_bounds__(256) void k_colscan(int* __restrict__ cnt_m,
                                                 int* __restrict__ gcount, int nb) {
  __shared__ int sh[256];
  int tid = threadIdx.x;
  int b = blockIdx.x;
  int v = cnt_m[(size_t)tid * nb + b];
  sh[tid] = v;
  __syncthreads();
  for (int off = 1; off < 256; off <<= 1) {
    int t = (tid >= off) ? sh[tid - off] : 0;
    __syncthreads();
    sh[tid] += t;
    __syncthreads();
  }
  cnt_m[(size_t)tid * nb + b] = sh[tid] - v;  // exclusive over blocks
  if (tid == 255) gcount[b] = sh[255];
}

// ------ scan bucket totals -> base[0..nb]  (block 0) ; WW/bw precompute (block 1)
__global__ __launch_bounds__(1024) void k_bscan(const int* __restrict__ gcount,
                                                int* __restrict__ base, int nb,
                                                const float* __restrict__ W1,
                                                const float* __restrict__ W2,
                                                const float* __restrict__ b1,
                                                float* __restrict__ WW,
                                                float* __restrict__ bw) {
  __shared__ int sh[1024];
  __shared__ float w1[4096], w2[4096];
  int tid = threadIdx.x;
  if (blockIdx.x == 0) {
    int v = (tid < nb) ? gcount[tid] : 0;
    sh[tid] = v;
    __syncthreads();
    for (int off = 1; off < 1024; off <<= 1) {
      int t = (tid >= off) ? sh[tid - off] : 0;
      __syncthreads();
      sh[tid] += t;
      __syncthreads();
    }
    if (tid < nb) base[tid] = sh[tid] - v;
    if (tid == 0) base[nb] = sh[1023];
  } else {
    for (int i = tid; i < 4096; i += 1024) { w1[i] = W1[i]; w2[i] = W2[i]; }
    __syncthreads();
    for (int p = tid; p < 4096; p += 1024) {
      int k = p >> 6, d = p & 63;
      float a = 0.f;
      for (int m = 0; m < 64; ++m) a += w1[k * 64 + m] * w2[m * 64 + d];
      WW[p] = a;
    }
    if (tid < 64) {
      float a = 0.f;
      for (int k = 0; k < 64; ++k) a += b1[k] * w2[k * 64 + tid];
      bw[tid] = a;
    }
  }
}

// ---------------- pass C: place edges, LDS cursors only, packed payload --------
// pairs[pos] = src | ((tgt & 127) << 20)   (requires n < 2^20)
__global__ __launch_bounds__(256) void k_bin2(const int* __restrict__ row,
                                              const int* __restrict__ col,
                                              const int* __restrict__ base,
                                              const int* __restrict__ cnt_m,
                                              int* __restrict__ pairs,
                                              int e, int nb, int chunk) {
  __shared__ int gl[NBMAX];
  __shared__ int lcur[NBMAX];
  int tid = threadIdx.x;
  int blk = blockIdx.x;
  for (int b = tid; b < nb; b += 256) {
    gl[b] = base[b] + cnt_m[(size_t)blk * nb + b];
    lcur[b] = 0;
  }
  __syncthreads();
  int lo = blk * chunk, hi = min(lo + chunk, e);
  for (int i = lo + tid; i < hi; i += 256) {
    int s = row[i], t = col[i];
    int b = t >> 7;
    int pos = gl[b] + atomicAdd(&lcur[b], 1);
    pairs[pos] = s | ((t & (TILE - 1)) << 20);
  }
}

// ---------------- per-tile CSR: node-ordered srcs, starts[], dinv ---------------
__global__ __launch_bounds__(256) void k_csr(const int* __restrict__ pairs,
                                             const int* __restrict__ base,
                                             int* __restrict__ starts,
                                             int* __restrict__ srcs,
                                             float* __restrict__ dinv,
                                             int n, int e) {
  __shared__ int cnt[TILE];
  __shared__ int cur[TILE];
  __shared__ int sc[TILE];
  int tid = threadIdx.x;
  int b = blockIdx.x;
  int tile0 = b * TILE;
  if (tid < TILE) cnt[tid] = 0;
  __syncthreads();
  int e0 = base[b], e1 = base[b + 1];
  for (int i = e0 + tid; i < e1; i += 256)
    atomicAdd(&cnt[(unsigned)pairs[i] >> 20], 1);
  __syncthreads();
  int c = (tid < TILE) ? cnt[tid] : 0;
  if (tid < TILE) sc[tid] = c;
  __syncthreads();
  for (int off = 1; off < TILE; off <<= 1) {
    int t = (tid < TILE && tid >= off) ? sc[tid - off] : 0;
    __syncthreads();
    if (tid < TILE) sc[tid] += t;
    __syncthreads();
  }
  if (tid < TILE) {
    int excl = sc[tid] - c;
    cur[tid] = excl;
    int node = tile0 + tid;
    if (node < n) {
      starts[node] = e0 + excl;
      dinv[node] = rsqrtf(1.0f + (float)c);
    }
  }
  if (b == 0 && tid == 0) starts[n] = e;
  __syncthreads();
  for (int i = e0 + tid; i < e1; i += 256) {
    int p = pairs[i];
    int pos = atomicAdd(&cur[(unsigned)p >> 20], 1);
    srcs[e0 + pos] = p & 0xFFFFF;
  }
}

// ------- gather1: z1h = A_hat * xh (fp16 in/out), fused u = A_hat*1, unroll 8 ---
__global__ __launch_bounds__(256) void k_gather1(const int* __restrict__ starts,
                                                 const int* __restrict__ srcs,
                                                 const float* __restrict__ dinv,
                                                 const __half2* __restrict__ xh,
                                                 __half2* __restrict__ z1h,
                                                 float* __restrict__ u, int n) {
  int node = blockIdx.x * 8 + (threadIdx.x >> 5);
  if (node >= n) return;
  int lh = threadIdx.x & 31;
  int s = starts[node];
  int deg = starts[node + 1] - s;
  float dc = dinv[node];
  float2 hs = __half22float2(xh[(size_t)node * 32 + lh]);
  float ax = 0.f, ay = 0.f, wsum = 0.f;
  int j = 0;
  for (; j + 7 < deg; j += 8) {
    int r0 = srcs[s + j + 0], r1 = srcs[s + j + 1];
    int r2 = srcs[s + j + 2], r3 = srcs[s + j + 3];
    int r4 = srcs[s + j + 4], r5 = srcs[s + j + 5];
    int r6 = srcs[s + j + 6], r7 = srcs[s + j + 7];
    float w0 = dinv[r0], w1 = dinv[r1], w2 = dinv[r2], w3 = dinv[r3];
    float w4 = dinv[r4], w5 = dinv[r5], w6 = dinv[r6], w7 = dinv[r7];
    float2 v0 = __half22float2(xh[(size_t)r0 * 32 + lh]);
    float2 v1 = __half22float2(xh[(size_t)r1 * 32 + lh]);
    float2 v2 = __half22float2(xh[(size_t)r2 * 32 + lh]);
    float2 v3 = __half22float2(xh[(size_t)r3 * 32 + lh]);
    float2 v4 = __half22float2(xh[(size_t)r4 * 32 + lh]);
    float2 v5 = __half22float2(xh[(size_t)r5 * 32 + lh]);
    float2 v6 = __half22float2(xh[(size_t)r6 * 32 + lh]);
    float2 v7 = __half22float2(xh[(size_t)r7 * 32 + lh]);
    ax += w0 * v0.x + w1 * v1.x + w2 * v2.x + w3 * v3.x
        + w4 * v4.x + w5 * v5.x + w6 * v6.x + w7 * v7.x;
    ay += w0 * v0.y + w1 * v1.y + w2 * v2.y + w3 * v3.y
        + w4 * v4.y + w5 * v5.y + w6 * v6.y + w7 * v7.y;
    wsum += w0 + w1 + w2 + w3 + w4 + w5 + w6 + w7;
  }
  for (; j < deg; ++j) {
    int r = srcs[s + j];
    float w = dinv[r];
    float2 v = __half22float2(xh[(size_t)r * 32 + lh]);
    ax += w * v.x;
    ay += w * v.y;
    wsum += w;
  }
  float2 res;
  res.x = dc * dc * hs.x + dc * ax;
  res.y = dc * dc * hs.y + dc * ay;
  z1h[(size_t)node * 32 + lh] = __float22half2_rn(res);
  if (lh == 0) u[node] = dc * (dc + wsum);
}

// ------- gather2: z2 (fp32) = A_hat * z1h (fp16 in), unroll 8 -------------------
__global__ __launch_bounds__(256) void k_gather2(const int* __restrict__ starts,
                                                 const int* __restrict__ srcs,
                                                 const float* __restrict__ dinv,
                                                 const __half2* __restrict__ z1h,
                                                 float* __restrict__ z2, int n) {
  int node = blockIdx.x * 8 + (threadIdx.x >> 5);
  if (node >= n) return;
  int lh = threadIdx.x & 31;
  int s = starts[node];
  int deg = starts[node + 1] - s;
  float dc = dinv[node];
  float2 hs = __half22float2(z1h[(size_t)node * 32 + lh]);
  float ax = 0.f, ay = 0.f;
  int j = 0;
  for (; j + 7 < deg; j += 8) {
    int r0 = srcs[s + j + 0], r1 = srcs[s + j + 1];
    int r2 = srcs[s + j + 2], r3 = srcs[s + j + 3];
    int r4 = srcs[s + j + 4], r5 = srcs[s + j + 5];
    int r6 = srcs[s + j + 6], r7 = srcs[s + j + 7];
    float w0 = dinv[r0], w1 = dinv[r1], w2 = dinv[r2], w3 = dinv[r3];
    float w4 = dinv[r4], w5 = dinv[r5], w6 = dinv[r6], w7 = dinv[r7];
    float2 v0 = __half22float2(z1h[(size_t)r0 * 32 + lh]);
    float2 v1 = __half22float2(z1h[(size_t)r1 * 32 + lh]);
    float2 v2 = __half22float2(z1h[(size_t)r2 * 32 + lh]);
    float2 v3 = __half22float2(z1h[(size_t)r3 * 32 + lh]);
    float2 v4 = __half22float2(z1h[(size_t)r4 * 32 + lh]);
    float2 v5 = __half22float2(z1h[(size_t)r5 * 32 + lh]);
    float2 v6 = __half22float2(z1h[(size_t)r6 * 32 + lh]);
    float2 v7 = __half22float2(z1h[(size_t)r7 * 32 + lh]);
    ax += w0 * v0.x + w1 * v1.x + w2 * v2.x + w3 * v3.x
        + w4 * v4.x + w5 * v5.x + w6 * v6.x + w7 * v7.x;
    ay += w0 * v0.y + w1 * v1.y + w2 * v2.y + w3 * v3.y
        + w4 * v4.y + w5 * v5.y + w6 * v6.y + w7 * v7.y;
  }
  for (; j < deg; ++j) {
    int r = srcs[s + j];
    float w = dinv[r];
    float2 v = __half22float2(z1h[(size_t)r * 32 + lh]);
    ax += w * v.x;
    ay += w * v.y;
  }
  float2 res;
  res.x = dc * dc * hs.x + dc * ax;
  res.y = dc * dc * hs.y + dc * ay;
  *(float2*)(&z2[(size_t)node * 64 + lh * 2]) = res;
}

// ---------------- pool z2 rows, u, and counts (batch sorted) --------------------
__global__ void k_pool2(const float* __restrict__ z2, const float* __restrict__ u,
                        const int* __restrict__ batch, float* __restrict__ S,
                        float* __restrict__ T, float* __restrict__ cntf, int n) {
  int d = threadIdx.x;
  int start = blockIdx.x * 64;
  if (start >= n) return;
  int end = min(start + 64, n);
  int curg = batch[start];
  float acc = 0.f, cnt = 0.f, ua = 0.f;
  for (int i = start; i < end; ++i) {
    int g = batch[i];
    if (g != curg) {
      unsafeAtomicAdd(&S[curg * 64 + d], acc);
      if (d == 0) {
        unsafeAtomicAdd(&cntf[curg], cnt);
        unsafeAtomicAdd(&T[curg], ua);
      }
      acc = 0.f; cnt = 0.f; ua = 0.f;
      curg = g;
    }
    acc += z2[(size_t)i * 64 + d];
    if (d == 0) { cnt += 1.f; ua += u[i]; }
  }
  unsafeAtomicAdd(&S[curg * 64 + d], acc);
  if (d == 0) {
    unsafeAtomicAdd(&cntf[curg], cnt);
    unsafeAtomicAdd(&T[curg], ua);
  }
}

// ---------------- final: out[g] = (S[g]@WW + T[g]*bw)/cnt + b2 ------------------
__global__ __launch_bounds__(256) void k_final2(const float* __restrict__ S,
                                                const float* __restrict__ T,
                                                const float* __restrict__ cntf,
                                                const float* __restrict__ WW,
                                                const float* __restrict__ bw,
                                                const float* __restrict__ b2,
                                                float* __restrict__ out) {
  __shared__ float sS[4096], sW[4096];
  int tid = threadIdx.x;
  for (int i = tid; i < 4096; i += 256) { sS[i] = S[i]; sW[i] = WW[i]; }
  __syncthreads();
  for (int p = tid; p < 4096; p += 256) {
    int g = p >> 6, d = p & 63;
    float a = 0.f;
    for (int k = 0; k < 64; ++k) a += sS[g * 64 + k] * sW[k * 64 + d];
    float c = fmaxf(cntf[g], 1.0f);
    out[p] = (a + T[g] * bw[d]) / c + b2[d];
  }
}

extern "C" void kernel_launch(void* const* d_in, const int* in_sizes, int n_in,
                              void* d_out, int out_size, void* d_ws, size_t ws_size,
                              hipStream_t stream) {
  const float* x = (const float*)d_in[0];
  const int* ei = (const int*)d_in[1];
  const int* bat = (const int*)d_in[2];
  const float* W1 = (const float*)d_in[3];
  const float* b1 = (const float*)d_in[4];
  const float* W2 = (const float*)d_in[5];
  const float* b2 = (const float*)d_in[6];
  float* out = (float*)d_out;

  int n = in_sizes[0] / 64;  // 100000
  int e = in_sizes[1] / 2;   // 1000000
  const int* rowp = ei;      // sources
  const int* colp = ei + e;  // targets
  int nb = (n + TILE - 1) / TILE;      // 782 buckets (< NBMAX)
  int chunk = (e + NBLK - 1) / NBLK;   // edges per binning block

  // workspace: [S][cntf][T] (zeroed by k_cnt blk0; contiguous 4224 floats) |
  // gcount, base, cnt_m, dinv, starts, srcs, u, WW, bw, xh, z1h, z2. ~47 MB.
  char* ws = (char*)d_ws;
  size_t off = 0;
  auto alloc = [&](size_t elems) {
    void* p = ws + off;
    off += ((elems * 4 + 255) & ~(size_t)255);
    return p;
  };
  float* S = (float*)alloc(NG * DFEAT);   // 4096 floats
  float* cntf = (float*)alloc(NG);        // 64 floats (256B-aligned block)
  float* T = (float*)alloc(NG);           // 64 floats -> S..T contiguous 4224
  int* gcount = (int*)alloc(nb);
  int* base = (int*)alloc(nb + 1);
  int* cnt_m = (int*)alloc((size_t)NBLK * nb);
  float* dinv = (float*)alloc(n);
  int* starts = (int*)alloc(n + 1);
  int* srcs = (int*)alloc(e);
  float* u = (float*)alloc(n);
  float* WW = (float*)alloc(DFEAT * DFEAT);
  float* bw = (float*)alloc(DFEAT);
  __half2* xh = (__half2*)alloc((size_t)n * 32);   // n*64 halves
  __half2* z1h = (__half2*)alloc((size_t)n * 32);  // n*64 halves
  float* z2 = (float*)alloc((size_t)n * 64);
  int* pairs = (int*)z2;  // dead after k_csr; z2 first written by gather2

  int nbw = (n + 7) / 8;  // gathers: 2 nodes/wave, 8 per block
  int n32 = n * 32;       // half2 count

  k_cnt<<<NBLK, 256, 0, stream>>>(colp, cnt_m, S, x, xh, e, nb, chunk, n32);
  k_colscan<<<nb, 256, 0, stream>>>(cnt_m, gcount, nb);
  k_bscan<<<2, 1024, 0, stream>>>(gcount, base, nb, W1, W2, b1, WW, bw);
  k_bin2<<<NBLK, 256, 0, stream>>>(rowp, colp, base, cnt_m, pairs, e, nb, chunk);
  k_csr<<<nb, 256, 0, stream>>>(pairs, base, starts, srcs, dinv, n, e);

  // layer 1: z1h = A_hat * xh (+ fused u) ; layer 2: z2 = A_hat * z1h
  k_gather1<<<nbw, 256, 0, stream>>>(starts, srcs, dinv, xh, z1h, u, n);
  k_gather2<<<nbw, 256, 0, stream>>>(starts, srcs, dinv, z1h, z2, n);

  // pool + tiny final matmul
  k_pool2<<<(n + 63) / 64, 64, 0, stream>>>(z2, u, bat, S, T, cntf, n);
  k_final2<<<1, 256, 0, stream>>>(S, T, cntf, WW, bw, b2, out);
}

// Round 12
// 235.357 us; speedup vs baseline: 1.0101x; 1.0101x over previous
//
#include <hip/hip_runtime.h>
#include <hip/hip_fp16.h>

#define DFEAT 64
#define NG 64
#define TILE 128        // nodes per bucket/tile (bucket = tgt >> 7)
#define NBLK 256        // binning blocks
#define NBMAX 1024      // max buckets supported in LDS

// ------ pass A (fused): zero S/T/cntf + bucket histogram + fp32->fp16 convert ---
__global__ __launch_bounds__(256) void k_cnt(const int* __restrict__ col,
                                             int* __restrict__ cnt_m,
                                             float* __restrict__ zeroreg,
                                             const float* __restrict__ x,
                                             __half2* __restrict__ xh,
                                             int e, int nb, int chunk, int n32) {
  __shared__ int hist[NBMAX];
  int tid = threadIdx.x;
  int blk = blockIdx.x;
  if (blk == 0) {
    for (int i = tid; i < 4224; i += 256) zeroreg[i] = 0.f;  // S+cntf+T
  }
  for (int b = tid; b < nb; b += 256) hist[b] = 0;
  __syncthreads();
  int lo = blk * chunk, hi = min(lo + chunk, e);
  for (int i = lo + tid; i < hi; i += 256)
    atomicAdd(&hist[col[i] >> 7], 1);
  __syncthreads();
  for (int b = tid; b < nb; b += 256)
    cnt_m[(size_t)blk * nb + b] = hist[b];
  // fused fp16 conversion (grid-stride)
  for (int i = blk * 256 + tid; i < n32; i += NBLK * 256) {
    float2 v = ((const float2*)x)[i];
    xh[i] = __float22half2_rn(v);
  }
}

// ---------------- pass B: per-bucket scan over blocks (in place) + totals -------
__global__ __launch_bounds__(256) void k_colscan(int* __restrict__ cnt_m,
                                                 int* __restrict__ gcount, int nb) {
  __shared__ int sh[256];
  int tid = threadIdx.x;
  int b = blockIdx.x;
  int v = cnt_m[(size_t)tid * nb + b];
  sh[tid] = v;
  __syncthreads();
  for (int off = 1; off < 256; off <<= 1) {
    int t = (tid >= off) ? sh[tid - off] : 0;
    __syncthreads();
    sh[tid] += t;
    __syncthreads();
  }
  cnt_m[(size_t)tid * nb + b] = sh[tid] - v;  // exclusive over blocks
  if (tid == 255) gcount[b] = sh[255];
}

// ------ scan bucket totals -> base[0..nb]  (block 0) ; WW/bw precompute (block 1)
__global__ __launch_bounds__(1024) void k_bscan(const int* __restrict__ gcount,
                                                int* __restrict__ base, int nb,
                                                const float* __restrict__ W1,
                                                const float* __restrict__ W2,
                                                const float* __restrict__ b1,
                                                float* __restrict__ WW,
                                                float* __restrict__ bw) {
  __shared__ int sh[1024];
  __shared__ float w1[4096], w2[4096];
  int tid = threadIdx.x;
  if (blockIdx.x == 0) {
    int v = (tid < nb) ? gcount[tid] : 0;
    sh[tid] = v;
    __syncthreads();
    for (int off = 1; off < 1024; off <<= 1) {
      int t = (tid >= off) ? sh[tid - off] : 0;
      __syncthreads();
      sh[tid] += t;
      __syncthreads();
    }
    if (tid < nb) base[tid] = sh[tid] - v;
    if (tid == 0) base[nb] = sh[1023];
  } else {
    for (int i = tid; i < 4096; i += 1024) { w1[i] = W1[i]; w2[i] = W2[i]; }
    __syncthreads();
    for (int p = tid; p < 4096; p += 1024) {
      int k = p >> 6, d = p & 63;
      float a = 0.f;
      for (int m = 0; m < 64; ++m) a += w1[k * 64 + m] * w2[m * 64 + d];
      WW[p] = a;
    }
    if (tid < 64) {
      float a = 0.f;
      for (int k = 0; k < 64; ++k) a += b1[k] * w2[k * 64 + tid];
      bw[tid] = a;
    }
  }
}

// ---------------- pass C: place edges, LDS cursors only, packed payload --------
// pairs[pos] = src | ((tgt & 127) << 20)   (requires n < 2^20)
__global__ __launch_bounds__(256) void k_bin2(const int* __restrict__ row,
                                              const int* __restrict__ col,
                                              const int* __restrict__ base,
                                              const int* __restrict__ cnt_m,
                                              int* __restrict__ pairs,
                                              int e, int nb, int chunk) {
  __shared__ int gl[NBMAX];
  __shared__ int lcur[NBMAX];
  int tid = threadIdx.x;
  int blk = blockIdx.x;
  for (int b = tid; b < nb; b += 256) {
    gl[b] = base[b] + cnt_m[(size_t)blk * nb + b];
    lcur[b] = 0;
  }
  __syncthreads();
  int lo = blk * chunk, hi = min(lo + chunk, e);
  for (int i = lo + tid; i < hi; i += 256) {
    int s = row[i], t = col[i];
    int b = t >> 7;
    int pos = gl[b] + atomicAdd(&lcur[b], 1);
    pairs[pos] = s | ((t & (TILE - 1)) << 20);
  }
}

// ---------------- per-tile CSR: node-ordered srcs, starts[], dinv ---------------
__global__ __launch_bounds__(256) void k_csr(const int* __restrict__ pairs,
                                             const int* __restrict__ base,
                                             int* __restrict__ starts,
                                             int* __restrict__ srcs,
                                             float* __restrict__ dinv,
                                             int n, int e) {
  __shared__ int cnt[TILE];
  __shared__ int cur[TILE];
  __shared__ int sc[TILE];
  int tid = threadIdx.x;
  int b = blockIdx.x;
  int tile0 = b * TILE;
  if (tid < TILE) cnt[tid] = 0;
  __syncthreads();
  int e0 = base[b], e1 = base[b + 1];
  for (int i = e0 + tid; i < e1; i += 256)
    atomicAdd(&cnt[(unsigned)pairs[i] >> 20], 1);
  __syncthreads();
  int c = (tid < TILE) ? cnt[tid] : 0;
  if (tid < TILE) sc[tid] = c;
  __syncthreads();
  for (int off = 1; off < TILE; off <<= 1) {
    int t = (tid < TILE && tid >= off) ? sc[tid - off] : 0;
    __syncthreads();
    if (tid < TILE) sc[tid] += t;
    __syncthreads();
  }
  if (tid < TILE) {
    int excl = sc[tid] - c;
    cur[tid] = excl;
    int node = tile0 + tid;
    if (node < n) {
      starts[node] = e0 + excl;
      dinv[node] = rsqrtf(1.0f + (float)c);
    }
  }
  if (b == 0 && tid == 0) starts[n] = e;
  __syncthreads();
  for (int i = e0 + tid; i < e1; i += 256) {
    int p = pairs[i];
    int pos = atomicAdd(&cur[(unsigned)p >> 20], 1);
    srcs[e0 + pos] = p & 0xFFFFF;
  }
}

// ------- gather1: z1h = A_hat * xh (fp16 in/out), fused u = A_hat*1, unroll 8 ---
__global__ __launch_bounds__(256) void k_gather1(const int* __restrict__ starts,
                                                 const int* __restrict__ srcs,
                                                 const float* __restrict__ dinv,
                                                 const __half2* __restrict__ xh,
                                                 __half2* __restrict__ z1h,
                                                 float* __restrict__ u, int n) {
  int node = blockIdx.x * 8 + (threadIdx.x >> 5);
  if (node >= n) return;
  int lh = threadIdx.x & 31;
  int s = starts[node];
  int deg = starts[node + 1] - s;
  float dc = dinv[node];
  float2 hs = __half22float2(xh[(size_t)node * 32 + lh]);
  float ax = 0.f, ay = 0.f, wsum = 0.f;
  int j = 0;
  for (; j + 7 < deg; j += 8) {
    int r0 = srcs[s + j + 0], r1 = srcs[s + j + 1];
    int r2 = srcs[s + j + 2], r3 = srcs[s + j + 3];
    int r4 = srcs[s + j + 4], r5 = srcs[s + j + 5];
    int r6 = srcs[s + j + 6], r7 = srcs[s + j + 7];
    float w0 = dinv[r0], w1 = dinv[r1], w2 = dinv[r2], w3 = dinv[r3];
    float w4 = dinv[r4], w5 = dinv[r5], w6 = dinv[r6], w7 = dinv[r7];
    float2 v0 = __half22float2(xh[(size_t)r0 * 32 + lh]);
    float2 v1 = __half22float2(xh[(size_t)r1 * 32 + lh]);
    float2 v2 = __half22float2(xh[(size_t)r2 * 32 + lh]);
    float2 v3 = __half22float2(xh[(size_t)r3 * 32 + lh]);
    float2 v4 = __half22float2(xh[(size_t)r4 * 32 + lh]);
    float2 v5 = __half22float2(xh[(size_t)r5 * 32 + lh]);
    float2 v6 = __half22float2(xh[(size_t)r6 * 32 + lh]);
    float2 v7 = __half22float2(xh[(size_t)r7 * 32 + lh]);
    ax += w0 * v0.x + w1 * v1.x + w2 * v2.x + w3 * v3.x
        + w4 * v4.x + w5 * v5.x + w6 * v6.x + w7 * v7.x;
    ay += w0 * v0.y + w1 * v1.y + w2 * v2.y + w3 * v3.y
        + w4 * v4.y + w5 * v5.y + w6 * v6.y + w7 * v7.y;
    wsum += w0 + w1 + w2 + w3 + w4 + w5 + w6 + w7;
  }
  for (; j < deg; ++j) {
    int r = srcs[s + j];
    float w = dinv[r];
    float2 v = __half22float2(xh[(size_t)r * 32 + lh]);
    ax += w * v.x;
    ay += w * v.y;
    wsum += w;
  }
  float2 res;
  res.x = dc * dc * hs.x + dc * ax;
  res.y = dc * dc * hs.y + dc * ay;
  z1h[(size_t)node * 32 + lh] = __float22half2_rn(res);
  if (lh == 0) u[node] = dc * (dc + wsum);
}

// ------- gather2+pool fused: 32 nodes/block (1024 thr), LDS z2, boundary flush --
__global__ __launch_bounds__(1024) void k_gather2p(const int* __restrict__ starts,
                                                   const int* __restrict__ srcs,
                                                   const float* __restrict__ dinv,
                                                   const __half2* __restrict__ z1h,
                                                   const float* __restrict__ u,
                                                   const int* __restrict__ batch,
                                                   float* __restrict__ S,
                                                   float* __restrict__ T,
                                                   float* __restrict__ cntf, int n) {
  __shared__ float zblk[32 * 64];  // 8 KB: this block's 32 z2 rows
  int tid = threadIdx.x;
  int nl = tid >> 5;               // local node 0..31
  int lh = tid & 31;
  int base0 = blockIdx.x * 32;
  int node = base0 + nl;
  if (node < n) {
    int s = starts[node];
    int deg = starts[node + 1] - s;
    float dc = dinv[node];
    float2 hs = __half22float2(z1h[(size_t)node * 32 + lh]);
    float ax = 0.f, ay = 0.f;
    int j = 0;
    for (; j + 7 < deg; j += 8) {
      int r0 = srcs[s + j + 0], r1 = srcs[s + j + 1];
      int r2 = srcs[s + j + 2], r3 = srcs[s + j + 3];
      int r4 = srcs[s + j + 4], r5 = srcs[s + j + 5];
      int r6 = srcs[s + j + 6], r7 = srcs[s + j + 7];
      float w0 = dinv[r0], w1 = dinv[r1], w2 = dinv[r2], w3 = dinv[r3];
      float w4 = dinv[r4], w5 = dinv[r5], w6 = dinv[r6], w7 = dinv[r7];
      float2 v0 = __half22float2(z1h[(size_t)r0 * 32 + lh]);
      float2 v1 = __half22float2(z1h[(size_t)r1 * 32 + lh]);
      float2 v2 = __half22float2(z1h[(size_t)r2 * 32 + lh]);
      float2 v3 = __half22float2(z1h[(size_t)r3 * 32 + lh]);
      float2 v4 = __half22float2(z1h[(size_t)r4 * 32 + lh]);
      float2 v5 = __half22float2(z1h[(size_t)r5 * 32 + lh]);
      float2 v6 = __half22float2(z1h[(size_t)r6 * 32 + lh]);
      float2 v7 = __half22float2(z1h[(size_t)r7 * 32 + lh]);
      ax += w0 * v0.x + w1 * v1.x + w2 * v2.x + w3 * v3.x
          + w4 * v4.x + w5 * v5.x + w6 * v6.x + w7 * v7.x;
      ay += w0 * v0.y + w1 * v1.y + w2 * v2.y + w3 * v3.y
          + w4 * v4.y + w5 * v5.y + w6 * v6.y + w7 * v7.y;
    }
    for (; j < deg; ++j) {
      int r = srcs[s + j];
      float w = dinv[r];
      float2 v = __half22float2(z1h[(size_t)r * 32 + lh]);
      ax += w * v.x;
      ay += w * v.y;
    }
    zblk[nl * 64 + lh * 2] = dc * dc * hs.x + dc * ax;
    zblk[nl * 64 + lh * 2 + 1] = dc * dc * hs.y + dc * ay;
  }
  __syncthreads();
  int m = min(32, n - base0);
  if (m <= 0) return;
  if (tid < 64) {
    // wave 0: flush S rows with graph-boundary batching (batch is sorted)
    int curg = batch[base0];
    float acc = 0.f;
    for (int i = 0; i < m; ++i) {
      int g = batch[base0 + i];
      if (g != curg) {
        unsafeAtomicAdd(&S[curg * 64 + tid], acc);
        acc = 0.f;
        curg = g;
      }
      acc += zblk[i * 64 + tid];
    }
    unsafeAtomicAdd(&S[curg * 64 + tid], acc);
  } else if (tid == 64) {
    // wave 1 lane 0: flush T (u-sum) and cntf
    int curg = batch[base0];
    float cnt = 0.f, ua = 0.f;
    for (int i = 0; i < m; ++i) {
      int g = batch[base0 + i];
      if (g != curg) {
        unsafeAtomicAdd(&cntf[curg], cnt);
        unsafeAtomicAdd(&T[curg], ua);
        cnt = 0.f; ua = 0.f;
        curg = g;
      }
      cnt += 1.f;
      ua += u[base0 + i];
    }
    unsafeAtomicAdd(&cntf[curg], cnt);
    unsafeAtomicAdd(&T[curg], ua);
  }
}

// ---------------- final: out[g] = (S[g]@WW + T[g]*bw)/cnt + b2 ------------------
__global__ __launch_bounds__(256) void k_final2(const float* __restrict__ S,
                                                const float* __restrict__ T,
                                                const float* __restrict__ cntf,
                                                const float* __restrict__ WW,
                                                const float* __restrict__ bw,
                                                const float* __restrict__ b2,
                                                float* __restrict__ out) {
  __shared__ float sS[4096], sW[4096];
  int tid = threadIdx.x;
  for (int i = tid; i < 4096; i += 256) { sS[i] = S[i]; sW[i] = WW[i]; }
  __syncthreads();
  for (int p = tid; p < 4096; p += 256) {
    int g = p >> 6, d = p & 63;
    float a = 0.f;
    for (int k = 0; k < 64; ++k) a += sS[g * 64 + k] * sW[k * 64 + d];
    float c = fmaxf(cntf[g], 1.0f);
    out[p] = (a + T[g] * bw[d]) / c + b2[d];
  }
}

extern "C" void kernel_launch(void* const* d_in, const int* in_sizes, int n_in,
                              void* d_out, int out_size, void* d_ws, size_t ws_size,
                              hipStream_t stream) {
  const float* x = (const float*)d_in[0];
  const int* ei = (const int*)d_in[1];
  const int* bat = (const int*)d_in[2];
  const float* W1 = (const float*)d_in[3];
  const float* b1 = (const float*)d_in[4];
  const float* W2 = (const float*)d_in[5];
  const float* b2 = (const float*)d_in[6];
  float* out = (float*)d_out;

  int n = in_sizes[0] / 64;  // 100000
  int e = in_sizes[1] / 2;   // 1000000
  const int* rowp = ei;      // sources
  const int* colp = ei + e;  // targets
  int nb = (n + TILE - 1) / TILE;      // 782 buckets (< NBMAX)
  int chunk = (e + NBLK - 1) / NBLK;   // edges per binning block

  // workspace: [S][cntf][T] (zeroed by k_cnt blk0; contiguous 4224 floats) |
  // gcount, base, cnt_m, dinv, starts, srcs, u, WW, bw, xh, z1h, pairs. ~25 MB.
  char* ws = (char*)d_ws;
  size_t off = 0;
  auto alloc = [&](size_t elems) {
    void* p = ws + off;
    off += ((elems * 4 + 255) & ~(size_t)255);
    return p;
  };
  float* S = (float*)alloc(NG * DFEAT);   // 4096 floats
  float* cntf = (float*)alloc(NG);        // 64
  float* T = (float*)alloc(NG);           // 64 -> S..T contiguous 4224 floats
  int* gcount = (int*)alloc(nb);
  int* base = (int*)alloc(nb + 1);
  int* cnt_m = (int*)alloc((size_t)NBLK * nb);
  float* dinv = (float*)alloc(n);
  int* starts = (int*)alloc(n + 1);
  int* srcs = (int*)alloc(e);
  float* u = (float*)alloc(n);
  float* WW = (float*)alloc(DFEAT * DFEAT);
  float* bw = (float*)alloc(DFEAT);
  __half2* xh = (__half2*)alloc((size_t)n * 32);   // n*64 halves
  __half2* z1h = (__half2*)alloc((size_t)n * 32);  // n*64 halves
  int* pairs = (int*)alloc(e);                     // target-binned packed edges

  int nbw = (n + 7) / 8;    // gather1: 2 nodes/wave, 8/block (256 thr)
  int nbp = (n + 31) / 32;  // gather2p: 32 nodes/block (1024 thr)
  int n32 = n * 32;         // half2 count

  k_cnt<<<NBLK, 256, 0, stream>>>(colp, cnt_m, S, x, xh, e, nb, chunk, n32);
  k_colscan<<<nb, 256, 0, stream>>>(cnt_m, gcount, nb);
  k_bscan<<<2, 1024, 0, stream>>>(gcount, base, nb, W1, W2, b1, WW, bw);
  k_bin2<<<NBLK, 256, 0, stream>>>(rowp, colp, base, cnt_m, pairs, e, nb, chunk);
  k_csr<<<nb, 256, 0, stream>>>(pairs, base, starts, srcs, dinv, n, e);

  // layer 1: z1h = A_hat * xh (+ fused u)
  k_gather1<<<nbw, 256, 0, stream>>>(starts, srcs, dinv, xh, z1h, u, n);
  // layer 2 fused with pooling: S/T/cntf accumulated directly
  k_gather2p<<<nbp, 1024, 0, stream>>>(starts, srcs, dinv, z1h, u, bat, S, T, cntf, n);

  k_final2<<<1, 256, 0, stream>>>(S, T, cntf, WW, bw, b2, out);
}

// Round 13
// 231.004 us; speedup vs baseline: 1.0291x; 1.0188x over previous
//
#include <hip/hip_runtime.h>
#include <hip/hip_fp16.h>

#define DFEAT 64
#define NG 64
#define TILE 128        // nodes per bucket/tile (bucket = tgt >> 7)
#define NBLK 256        // binning blocks
#define NBMAX 1024      // max buckets supported in LDS

// ---------------- pass A: per-block-chunk bucket histogram -> cnt_m[blk][b] -----
__global__ __launch_bounds__(256) void k_cnt(const int* __restrict__ col,
                                             int* __restrict__ cnt_m,
                                             int e, int nb, int chunk) {
  __shared__ int hist[NBMAX];
  int tid = threadIdx.x;
  int blk = blockIdx.x;
  for (int b = tid; b < nb; b += 256) hist[b] = 0;
  __syncthreads();
  int lo = blk * chunk, hi = min(lo + chunk, e);
  for (int i = lo + tid; i < hi; i += 256)
    atomicAdd(&hist[col[i] >> 7], 1);
  __syncthreads();
  for (int b = tid; b < nb; b += 256)
    cnt_m[(size_t)blk * nb + b] = hist[b];
}

// ---------------- pass B: per-bucket scan over blocks (in place) + totals -------
__global__ __launch_bounds__(256) void k_colscan(int* __restrict__ cnt_m,
                                                 int* __restrict__ gcount, int nb) {
  __shared__ int sh[256];
  int tid = threadIdx.x;
  int b = blockIdx.x;
  int v = cnt_m[(size_t)tid * nb + b];
  sh[tid] = v;
  __syncthreads();
  for (int off = 1; off < 256; off <<= 1) {
    int t = (tid >= off) ? sh[tid - off] : 0;
    __syncthreads();
    sh[tid] += t;
    __syncthreads();
  }
  cnt_m[(size_t)tid * nb + b] = sh[tid] - v;  // exclusive over blocks
  if (tid == 255) gcount[b] = sh[255];
}

// ---------------- scan bucket totals -> base[0..nb] ----------------------------
__global__ __launch_bounds__(1024) void k_bscan(const int* __restrict__ gcount,
                                                int* __restrict__ base, int nb) {
  __shared__ int sh[1024];
  int tid = threadIdx.x;
  int v = (tid < nb) ? gcount[tid] : 0;
  sh[tid] = v;
  __syncthreads();
  for (int off = 1; off < 1024; off <<= 1) {
    int t = (tid >= off) ? sh[tid - off] : 0;
    __syncthreads();
    sh[tid] += t;
    __syncthreads();
  }
  if (tid < nb) base[tid] = sh[tid] - v;
  if (tid == 0) base[nb] = sh[1023];
}

// ---------------- pass C: place edges, LDS cursors only, packed payload --------
// pairs[pos] = src | ((tgt & 127) << 20)   (requires n < 2^20)
__global__ __launch_bounds__(256) void k_bin2(const int* __restrict__ row,
                                              const int* __restrict__ col,
                                              const int* __restrict__ base,
                                              const int* __restrict__ cnt_m,
                                              int* __restrict__ pairs,
                                              int e, int nb, int chunk) {
  __shared__ int gl[NBMAX];
  __shared__ int lcur[NBMAX];
  int tid = threadIdx.x;
  int blk = blockIdx.x;
  for (int b = tid; b < nb; b += 256) {
    gl[b] = base[b] + cnt_m[(size_t)blk * nb + b];
    lcur[b] = 0;
  }
  __syncthreads();
  int lo = blk * chunk, hi = min(lo + chunk, e);
  for (int i = lo + tid; i < hi; i += 256) {
    int s = row[i], t = col[i];
    int b = t >> 7;
    int pos = gl[b] + atomicAdd(&lcur[b], 1);
    pairs[pos] = s | ((t & (TILE - 1)) << 20);
  }
}

// ---------------- per-tile CSR: node-ordered srcs, starts[], dinv ---------------
__global__ __launch_bounds__(256) void k_csr(const int* __restrict__ pairs,
                                             const int* __restrict__ base,
                                             int* __restrict__ starts,
                                             int* __restrict__ srcs,
                                             float* __restrict__ dinv,
                                             int n, int e) {
  __shared__ int cnt[TILE];
  __shared__ int cur[TILE];
  __shared__ int sc[TILE];
  int tid = threadIdx.x;
  int b = blockIdx.x;
  int tile0 = b * TILE;
  if (tid < TILE) cnt[tid] = 0;
  __syncthreads();
  int e0 = base[b], e1 = base[b + 1];
  for (int i = e0 + tid; i < e1; i += 256)
    atomicAdd(&cnt[(unsigned)pairs[i] >> 20], 1);
  __syncthreads();
  int c = (tid < TILE) ? cnt[tid] : 0;
  if (tid < TILE) sc[tid] = c;
  __syncthreads();
  for (int off = 1; off < TILE; off <<= 1) {
    int t = (tid < TILE && tid >= off) ? sc[tid - off] : 0;
    __syncthreads();
    if (tid < TILE) sc[tid] += t;
    __syncthreads();
  }
  if (tid < TILE) {
    int excl = sc[tid] - c;
    cur[tid] = excl;
    int node = tile0 + tid;
    if (node < n) {
      starts[node] = e0 + excl;
      dinv[node] = rsqrtf(1.0f + (float)c);
    }
  }
  if (b == 0 && tid == 0) starts[n] = e;
  __syncthreads();
  for (int i = e0 + tid; i < e1; i += 256) {
    int p = pairs[i];
    int pos = atomicAdd(&cur[(unsigned)p >> 20], 1);
    srcs[e0 + pos] = p & 0xFFFFF;
  }
}

// ---------------- x (fp32) -> xh (fp16), element-pair wise ----------------------
__global__ void k_half(const float* __restrict__ x, __half2* __restrict__ xh,
                       int n32) {
  int i = blockIdx.x * 256 + threadIdx.x;
  if (i < n32) {
    float2 v = ((const float2*)x)[i];
    xh[i] = __float22half2_rn(v);
  }
}

// ---------------- WW = W1@W2 (64x64), bw = b1^T @ W2 ----------------------------
__global__ __launch_bounds__(256) void k_w12(const float* __restrict__ W1,
                                             const float* __restrict__ W2,
                                             const float* __restrict__ b1,
                                             float* __restrict__ WW,
                                             float* __restrict__ bw) {
  __shared__ float w1[4096], w2[4096];
  int tid = threadIdx.x;
  for (int i = tid; i < 4096; i += 256) { w1[i] = W1[i]; w2[i] = W2[i]; }
  __syncthreads();
  for (int p = tid; p < 4096; p += 256) {
    int k = p >> 6, d = p & 63;
    float a = 0.f;
    for (int m = 0; m < 64; ++m) a += w1[k * 64 + m] * w2[m * 64 + d];
    WW[p] = a;
  }
  if (tid < 64) {
    float a = 0.f;
    for (int k = 0; k < 64; ++k) a += b1[k] * w2[k * 64 + tid];
    bw[tid] = a;
  }
}

// ------- gather1: z1h = A_hat * xh (fp16 in/out), fused u = A_hat*1 -------------
// 2 nodes per wave; 32 lanes per node, each lane one __half2 (4 B) of the row.
__global__ __launch_bounds__(256) void k_gather1(const int* __restrict__ starts,
                                                 const int* __restrict__ srcs,
                                                 const float* __restrict__ dinv,
                                                 const __half2* __restrict__ xh,
                                                 __half2* __restrict__ z1h,
                                                 float* __restrict__ u, int n) {
  int node = blockIdx.x * 8 + (threadIdx.x >> 5);
  if (node >= n) return;
  int lh = threadIdx.x & 31;
  int s = starts[node];
  int deg = starts[node + 1] - s;
  float dc = dinv[node];
  float2 hs = __half22float2(xh[(size_t)node * 32 + lh]);
  float ax = 0.f, ay = 0.f, wsum = 0.f;
  int j = 0;
  for (; j + 3 < deg; j += 4) {
    int r0 = srcs[s + j + 0];
    int r1 = srcs[s + j + 1];
    int r2 = srcs[s + j + 2];
    int r3 = srcs[s + j + 3];
    float w0 = dinv[r0], w1 = dinv[r1], w2 = dinv[r2], w3 = dinv[r3];
    float2 v0 = __half22float2(xh[(size_t)r0 * 32 + lh]);
    float2 v1 = __half22float2(xh[(size_t)r1 * 32 + lh]);
    float2 v2 = __half22float2(xh[(size_t)r2 * 32 + lh]);
    float2 v3 = __half22float2(xh[(size_t)r3 * 32 + lh]);
    ax += w0 * v0.x + w1 * v1.x + w2 * v2.x + w3 * v3.x;
    ay += w0 * v0.y + w1 * v1.y + w2 * v2.y + w3 * v3.y;
    wsum += w0 + w1 + w2 + w3;
  }
  for (; j < deg; ++j) {
    int r = srcs[s + j];
    float w = dinv[r];
    float2 v = __half22float2(xh[(size_t)r * 32 + lh]);
    ax += w * v.x;
    ay += w * v.y;
    wsum += w;
  }
  float2 res;
  res.x = dc * dc * hs.x + dc * ax;
  res.y = dc * dc * hs.y + dc * ay;
  z1h[(size_t)node * 32 + lh] = __float22half2_rn(res);
  if (lh == 0) u[node] = dc * (dc + wsum);
}

// ------- gather2: z2 (fp32) = A_hat * z1h (fp16 in) -----------------------------
__global__ __launch_bounds__(256) void k_gather2(const int* __restrict__ starts,
                                                 const int* __restrict__ srcs,
                                                 const float* __restrict__ dinv,
                                                 const __half2* __restrict__ z1h,
                                                 float* __restrict__ z2, int n) {
  int node = blockIdx.x * 8 + (threadIdx.x >> 5);
  if (node >= n) return;
  int lh = threadIdx.x & 31;
  int s = starts[node];
  int deg = starts[node + 1] - s;
  float dc = dinv[node];
  float2 hs = __half22float2(z1h[(size_t)node * 32 + lh]);
  float ax = 0.f, ay = 0.f;
  int j = 0;
  for (; j + 3 < deg; j += 4) {
    int r0 = srcs[s + j + 0];
    int r1 = srcs[s + j + 1];
    int r2 = srcs[s + j + 2];
    int r3 = srcs[s + j + 3];
    float w0 = dinv[r0], w1 = dinv[r1], w2 = dinv[r2], w3 = dinv[r3];
    float2 v0 = __half22float2(z1h[(size_t)r0 * 32 + lh]);
    float2 v1 = __half22float2(z1h[(size_t)r1 * 32 + lh]);
    float2 v2 = __half22float2(z1h[(size_t)r2 * 32 + lh]);
    float2 v3 = __half22float2(z1h[(size_t)r3 * 32 + lh]);
    ax += w0 * v0.x + w1 * v1.x + w2 * v2.x + w3 * v3.x;
    ay += w0 * v0.y + w1 * v1.y + w2 * v2.y + w3 * v3.y;
  }
  for (; j < deg; ++j) {
    int r = srcs[s + j];
    float w = dinv[r];
    float2 v = __half22float2(z1h[(size_t)r * 32 + lh]);
    ax += w * v.x;
    ay += w * v.y;
  }
  float2 res;
  res.x = dc * dc * hs.x + dc * ax;
  res.y = dc * dc * hs.y + dc * ay;
  *(float2*)(&z2[(size_t)node * 64 + lh * 2]) = res;
}

// ---------------- pool z2 rows, u, and counts (batch sorted) --------------------
__global__ void k_pool2(const float* __restrict__ z2, const float* __restrict__ u,
                        const int* __restrict__ batch, float* __restrict__ S,
                        float* __restrict__ T, float* __restrict__ cntf, int n) {
  int d = threadIdx.x;
  int start = blockIdx.x * 64;
  if (start >= n) return;
  int end = min(start + 64, n);
  int curg = batch[start];
  float acc = 0.f, cnt = 0.f, ua = 0.f;
  for (int i = start; i < end; ++i) {
    int g = batch[i];
    if (g != curg) {
      unsafeAtomicAdd(&S[curg * 64 + d], acc);
      if (d == 0) {
        unsafeAtomicAdd(&cntf[curg], cnt);
        unsafeAtomicAdd(&T[curg], ua);
      }
      acc = 0.f; cnt = 0.f; ua = 0.f;
      curg = g;
    }
    acc += z2[(size_t)i * 64 + d];
    if (d == 0) { cnt += 1.f; ua += u[i]; }
  }
  unsafeAtomicAdd(&S[curg * 64 + d], acc);
  if (d == 0) {
    unsafeAtomicAdd(&cntf[curg], cnt);
    unsafeAtomicAdd(&T[curg], ua);
  }
}

// ---------------- final: out[g] = (S[g]@WW + T[g]*bw)/cnt + b2 ------------------
__global__ __launch_bounds__(256) void k_final2(const float* __restrict__ S,
                                                const float* __restrict__ T,
                                                const float* __restrict__ cntf,
                                                const float* __restrict__ WW,
                                                const float* __restrict__ bw,
                                                const float* __restrict__ b2,
                                                float* __restrict__ out) {
  __shared__ float sS[4096], sW[4096];
  int tid = threadIdx.x;
  for (int i = tid; i < 4096; i += 256) { sS[i] = S[i]; sW[i] = WW[i]; }
  __syncthreads();
  for (int p = tid; p < 4096; p += 256) {
    int g = p >> 6, d = p & 63;
    float a = 0.f;
    for (int k = 0; k < 64; ++k) a += sS[g * 64 + k] * sW[k * 64 + d];
    float c = fmaxf(cntf[g], 1.0f);
    out[p] = (a + T[g] * bw[d]) / c + b2[d];
  }
}

extern "C" void kernel_launch(void* const* d_in, const int* in_sizes, int n_in,
                              void* d_out, int out_size, void* d_ws, size_t ws_size,
                              hipStream_t stream) {
  const float* x = (const float*)d_in[0];
  const int* ei = (const int*)d_in[1];
  const int* bat = (const int*)d_in[2];
  const float* W1 = (const float*)d_in[3];
  const float* b1 = (const float*)d_in[4];
  const float* W2 = (const float*)d_in[5];
  const float* b2 = (const float*)d_in[6];
  float* out = (float*)d_out;

  int n = in_sizes[0] / 64;  // 100000
  int e = in_sizes[1] / 2;   // 1000000
  const int* rowp = ei;      // sources
  const int* colp = ei + e;  // targets
  int nb = (n + TILE - 1) / TILE;      // 782 buckets (< NBMAX)
  int chunk = (e + NBLK - 1) / NBLK;   // edges per binning block

  // workspace (4B alloc units): [S][cntf][T] zeroed | gcount, base, cnt_m,
  // dinv, starts, srcs, u, WW, bw, xh, z1h, z2 (pairs alias z2).  ~47 MB.
  char* ws = (char*)d_ws;
  size_t off = 0;
  auto alloc = [&](size_t elems) {
    void* p = ws + off;
    off += ((elems * 4 + 255) & ~(size_t)255);
    return p;
  };
  float* S = (float*)alloc(NG * DFEAT);
  float* cntf = (float*)alloc(NG);
  float* T = (float*)alloc(NG);
  size_t zbytes = off;
  int* gcount = (int*)alloc(nb);
  int* base = (int*)alloc(nb + 1);
  int* cnt_m = (int*)alloc((size_t)NBLK * nb);
  float* dinv = (float*)alloc(n);
  int* starts = (int*)alloc(n + 1);
  int* srcs = (int*)alloc(e);
  float* u = (float*)alloc(n);
  float* WW = (float*)alloc(DFEAT * DFEAT);
  float* bw = (float*)alloc(DFEAT);
  __half2* xh = (__half2*)alloc((size_t)n * 32);   // n*64 halves
  __half2* z1h = (__half2*)alloc((size_t)n * 32);  // n*64 halves
  float* z2 = (float*)alloc((size_t)n * 64);
  int* pairs = (int*)z2;  // dead after k_csr; z2 first written by gather2

  int nbw = (n + 7) / 8;  // gathers: 2 nodes/wave, 8 per block
  int n32 = n * 32;       // half2 count

  hipMemsetAsync(S, 0, zbytes, stream);
  k_cnt<<<NBLK, 256, 0, stream>>>(colp, cnt_m, e, nb, chunk);
  k_colscan<<<nb, 256, 0, stream>>>(cnt_m, gcount, nb);
  k_bscan<<<1, 1024, 0, stream>>>(gcount, base, nb);
  k_bin2<<<NBLK, 256, 0, stream>>>(rowp, colp, base, cnt_m, pairs, e, nb, chunk);
  k_csr<<<nb, 256, 0, stream>>>(pairs, base, starts, srcs, dinv, n, e);
  k_half<<<(n32 + 255) / 256, 256, 0, stream>>>(x, xh, n32);
  k_w12<<<1, 256, 0, stream>>>(W1, W2, b1, WW, bw);

  // layer 1: z1h = A_hat * xh (+ fused u) ; layer 2: z2 = A_hat * z1h
  k_gather1<<<nbw, 256, 0, stream>>>(starts, srcs, dinv, xh, z1h, u, n);
  k_gather2<<<nbw, 256, 0, stream>>>(starts, srcs, dinv, z1h, z2, n);

  // pool + tiny final matmul
  k_pool2<<<(n + 63) / 64, 64, 0, stream>>>(z2, u, bat, S, T, cntf, n);
  k_final2<<<1, 256, 0, stream>>>(S, T, cntf, WW, bw, b2, out);
}